// Round 7
// baseline (240.585 us; speedup 1.0000x reference)
//
#include <hip/hip_runtime.h>
#include <hip/hip_bf16.h>
#include <math.h>

#define BB 32
#define SS 4096
#define HH 256

typedef __bf16 bf16x8 __attribute__((ext_vector_type(8)));
typedef float f32x4 __attribute__((ext_vector_type(4)));

#define GLOBAL_AS __attribute__((address_space(1)))
#define LDS_AS    __attribute__((address_space(3)))

__device__ inline bf16x8 cvt8(const float4& x, const float4& y) {
    union { __hip_bfloat162 p[4]; bf16x8 v; } u;
    u.p[0] = __float22bfloat162_rn(make_float2(x.x, x.y));
    u.p[1] = __float22bfloat162_rn(make_float2(x.z, x.w));
    u.p[2] = __float22bfloat162_rn(make_float2(y.x, y.y));
    u.p[3] = __float22bfloat162_rn(make_float2(y.z, y.w));
    return u.v;
}

// tanh(x) = 1 - 2/(e^{2x}+1). Clamp-free: exp2 overflow -> +inf -> rcp=0 -> 1;
// underflow -> 0 -> 1-2 = -1. ~5 VALU ops.
__device__ inline float fast_tanh(float x) {
    float e = __builtin_amdgcn_exp2f(x * 2.8853900817779268f);  // 2*log2(e)
    return 1.f - 2.f * __builtin_amdgcn_rcpf(e + 1.f);
}

// ---------------------------------------------------------------------------
// Prep (unchanged): blocks 0..255 swizzle W2 -> bf16 MFMA-B order;
// blocks 256..287: qq[b][h] = hidden[b]@W1[:,h] + W1_b[h] + W2_b[h];
// block 288: M = sum_h |V_w[h]|  (upper bound on V.tanh; V_b cancels).
// w2sw[((kc*16+nt)*64+lane)*8+j] = W2[kc*32+(lane>>4)*8+j][nt*16+(lane&15)]
// ---------------------------------------------------------------------------
__global__ void prep_kernel(const float* __restrict__ W2_w,
                            ushort* __restrict__ w2sw,
                            const float* __restrict__ hidden,
                            const float* __restrict__ W1_w,
                            const float* __restrict__ W1_b,
                            const float* __restrict__ W2_b,
                            const float* __restrict__ V_w,
                            float* __restrict__ qq,
                            float* __restrict__ Mout) {
    __shared__ float red[HH];
    const int t = threadIdx.x;
    if (blockIdx.x < 256) {
        const int i = blockIdx.x * 256 + t;
        const int j    = i & 7;
        const int lane = (i >> 3) & 63;
        const int nt   = (i >> 9) & 15;
        const int kc   = i >> 13;
        const int k = kc * 32 + ((lane >> 4) & 3) * 8 + j;
        const int n = nt * 16 + (lane & 15);
        __hip_bfloat16 h = __float2bfloat16(W2_w[k * HH + n]);
        w2sw[i] = *(ushort*)&h;
    } else if (blockIdx.x < 256 + BB) {
        const int b = blockIdx.x - 256;
        red[t] = hidden[b * HH + t];
        __syncthreads();
        float acc = 0.f;
#pragma unroll 16
        for (int k = 0; k < HH; ++k)
            acc = fmaf(red[k], W1_w[k * HH + t], acc);
        qq[b * HH + t] = acc + W1_b[t] + W2_b[t];
    } else {
        red[t] = fabsf(V_w[t]);
        __syncthreads();
        for (int off = 128; off > 0; off >>= 1) {
            if (t < off) red[t] += red[t + off];
            __syncthreads();
        }
        if (t == 0) Mout[0] = red[0];
    }
}

// ---------------------------------------------------------------------------
// Fused score + partial-context v7: grid (SS/64, BB), block 256 = 4 waves
// (2m x 2n), 64-row tile. ROUND-6 LESSON: 2-deep ping-pong left each wave
// waiting on loads issued ONE iteration ago; with every wave on the chip in
// the same issue/wait convoy, effective latency = global queue-drain time
// (~2.6 us per 16 MB burst), not 375 ns -> all pipes <15% busy. v7 deepens
// the DMA pipeline to THREE buffers: chunks k+1,k+2 always in flight
// (vmcnt(12) steady / 6 / 0 tail), so each burst gets two full iterations
// to land; steady in-flight A = 2 blocks x 2 chunks x 8 KB = 32 KB/CU
// (> BWxLat share ~19 KB). LDS 72.3 KB dynamic -> 2 blocks/CU.
// A LDS layout keeps the r6 conflict-free XOR scheme (rule #21: linear DMA
// dest, source col pre-swizzled by 4*((lane&7)^(lane>>3)), read col XOR
// (row&7)*4). Buffer-reuse safety: STAGE(k+2) writes buf (k-1)%3 whose
// reads finished at iter k-1's lgkmcnt(0)+barrier.
// ---------------------------------------------------------------------------
__global__ __launch_bounds__(256, 2)
void score_ctx_kernel(const float* __restrict__ enc,
                      const ushort* __restrict__ w2sw,
                      const float* __restrict__ qq,
                      const float* __restrict__ V_w,
                      const float* __restrict__ Mptr,
                      float* __restrict__ wtilde,
                      float* __restrict__ part) {
    // layout: [0,49152) w2buf[3][16384B]; [49152,73728) abuf[3][8192B]
    // (accl[4][256]f aliases abuf[0] after the K-loop); [73728,73984) sc_lds
    extern __shared__ __align__(16) char smem[];
    float* sc_lds = (float*)(smem + 73728);
    float* accl   = (float*)(smem + 49152);    // alias abuf[0]

    const int t    = threadIdx.x;
    const int b    = blockIdx.y;
    const int c    = blockIdx.x;
    const int s0   = c * 64;
    const int wave = t >> 6;
    const int lane = t & 63;
    const int mw   = wave & 1;
    const int nw   = wave >> 1;
    const int l15  = lane & 15;
    const int quad = lane >> 4;

    const float* encA = enc + ((size_t)(b * SS + s0)) * HH;
    // A-stage: lds float idx = wave*512 + i*256 + lane*4 (linear DMA dest)
    //   -> row = wave*16 + i*8 + (lane>>3), stored col-group = (lane&7)*4
    //   -> fetch global col 4*((lane&7) ^ (lane>>3)) so that
    //      lds[row*32 + (col ^ (row&7)*4)] = enc[row][kc*32 + col]
    const int arow = wave * 16 + (lane >> 3);
    const int aswz = 4 * ((lane & 7) ^ (lane >> 3));

#define STAGE(KC, D)                                                          \
    do {                                                                      \
        const char* gw_ = (const char*)w2sw + (KC) * 16384 + t * 16;          \
        char* lw_ = smem + (D) * 16384 + wave * 1024;                         \
        _Pragma("unroll")                                                     \
        for (int i_ = 0; i_ < 4; ++i_)                                        \
            __builtin_amdgcn_global_load_lds(                                 \
                (const GLOBAL_AS void*)(gw_ + i_ * 4096),                     \
                (LDS_AS void*)(lw_ + i_ * 4096), 16, 0, 0);                   \
        _Pragma("unroll")                                                     \
        for (int i_ = 0; i_ < 2; ++i_)                                        \
            __builtin_amdgcn_global_load_lds(                                 \
                (const GLOBAL_AS void*)(encA + (size_t)(arow + i_ * 8) * HH + \
                                        (KC) * 32 + aswz),                    \
                (LDS_AS void*)(smem + 49152 + (D) * 8192 + wave * 2048 +      \
                               i_ * 1024), 16, 0, 0);                         \
    } while (0)

    f32x4 acc[2][8];
#pragma unroll
    for (int mt = 0; mt < 2; ++mt)
#pragma unroll
        for (int nt = 0; nt < 8; ++nt) acc[mt][nt] = (f32x4)0.f;

    STAGE(0, 0);   // prologue: chunks 0 and 1 in flight (12 vmem/wave)
    STAGE(1, 1);

#pragma unroll
    for (int kc = 0; kc < 8; ++kc) {
        const int cur = kc % 3;
        if (kc < 6) {
            STAGE(kc + 2, (kc + 2) % 3);                 // 18 in flight
            asm volatile("s_waitcnt vmcnt(12)" ::: "memory");  // kc landed
        } else if (kc == 6) {
            asm volatile("s_waitcnt vmcnt(6)" ::: "memory");
        } else {
            asm volatile("s_waitcnt vmcnt(0)" ::: "memory");
        }
        __builtin_amdgcn_s_barrier();                    // publish chunk kc

        const ushort* wbuf = (const ushort*)(smem + cur * 16384);
        const float*  abuf = (const float*)(smem + 49152 + cur * 8192);
        const int r0 = mw * 32 + l15;
        const int sx = (l15 & 7) * 4;                    // read-side swizzle
        const float4 ax0 = *(const float4*)&abuf[r0 * 32 + ((quad * 8) ^ sx)];
        const float4 ay0 = *(const float4*)&abuf[r0 * 32 + ((quad * 8 + 4) ^ sx)];
        const float4 ax1 = *(const float4*)&abuf[(r0 + 16) * 32 + ((quad * 8) ^ sx)];
        const float4 ay1 = *(const float4*)&abuf[(r0 + 16) * 32 + ((quad * 8 + 4) ^ sx)];
        const bf16x8 af0 = cvt8(ax0, ay0);
        const bf16x8 af1 = cvt8(ax1, ay1);
#pragma unroll
        for (int nt = 0; nt < 8; ++nt) {
            const bf16x8 bfr =
                *(const bf16x8*)&wbuf[((nw * 8 + nt) * 64 + lane) * 8];
            acc[0][nt] = __builtin_amdgcn_mfma_f32_16x16x32_bf16(
                af0, bfr, acc[0][nt], 0, 0, 0);
            acc[1][nt] = __builtin_amdgcn_mfma_f32_16x16x32_bf16(
                af1, bfr, acc[1][nt], 0, 0, 0);
        }
        // all LDS reads of this chunk consumed before the buffer is recycled
        asm volatile("s_waitcnt lgkmcnt(0)" ::: "memory");
        __builtin_amdgcn_s_barrier();
    }
#undef STAGE

    // Epilogue: C layout col = l15, local row = quad*4 + r.
    float p[2][4] = {{0.f, 0.f, 0.f, 0.f}, {0.f, 0.f, 0.f, 0.f}};
#pragma unroll
    for (int nt = 0; nt < 8; ++nt) {
        const int n = nw * 128 + nt * 16 + l15;
        const float qn = qq[b * HH + n];
        const float vn = V_w[n];
#pragma unroll
        for (int mt = 0; mt < 2; ++mt)
#pragma unroll
            for (int r = 0; r < 4; ++r)
                p[mt][r] = fmaf(vn, fast_tanh(qn + acc[mt][nt][r]), p[mt][r]);
    }
#pragma unroll
    for (int off = 1; off < 16; off <<= 1)
#pragma unroll
        for (int mt = 0; mt < 2; ++mt)
#pragma unroll
            for (int r = 0; r < 4; ++r)
                p[mt][r] += __shfl_xor(p[mt][r], off);

    if (nw == 0 && l15 == 0) {
#pragma unroll
        for (int mt = 0; mt < 2; ++mt)
            *(float4*)&sc_lds[mw * 32 + mt * 16 + quad * 4] =
                make_float4(p[mt][0], p[mt][1], p[mt][2], p[mt][3]);
    }
    __syncthreads();
    const float Mv = Mptr[0];
    if (nw == 1 && l15 == 0) {
#pragma unroll
        for (int mt = 0; mt < 2; ++mt) {
            const int row = mw * 32 + mt * 16 + quad * 4;
            float4 h = *(const float4*)&sc_lds[row];
            float4 v = make_float4(__expf(h.x + p[mt][0] - Mv),
                                   __expf(h.y + p[mt][1] - Mv),
                                   __expf(h.z + p[mt][2] - Mv),
                                   __expf(h.w + p[mt][3] - Mv));
            *(float4*)&sc_lds[row] = v;
            *(float4*)&wtilde[b * SS + s0 + row] = v;
        }
    }
    __syncthreads();

    // Local context partial over this block's 64 rows (enc slice L1/L2-hot).
    const int tr = t >> 6;
    const int h0 = (t & 63) * 4;
    float4 a = make_float4(0.f, 0.f, 0.f, 0.f);
    const float* ep = enc + ((size_t)(b * SS + s0)) * HH;
#pragma unroll
    for (int jj = 0; jj < 16; ++jj) {
        const int j = jj * 4 + tr;
        const float4 e = *(const float4*)(ep + (size_t)j * HH + h0);
        const float w = sc_lds[j];
        a.x = fmaf(w, e.x, a.x);
        a.y = fmaf(w, e.y, a.y);
        a.z = fmaf(w, e.z, a.z);
        a.w = fmaf(w, e.w, a.w);
    }
    *(float4*)&accl[tr * HH + h0] = a;
    __syncthreads();

    part[((size_t)(b * 64 + c)) * HH + t] =
        accl[0 * HH + t] + accl[1 * HH + t] + accl[2 * HH + t] +
        accl[3 * HH + t];
}

// ---------------------------------------------------------------------------
// Finish: grid (BB), block 256. l = sum_s wtilde; weights = wtilde/l;
// ctx = (sum_c part)/l.  (64 partials per b.)
// ---------------------------------------------------------------------------
__global__ __launch_bounds__(256)
void finish_kernel(const float* __restrict__ wtilde,
                   const float* __restrict__ part,
                   float* __restrict__ weights_out,
                   float* __restrict__ ctx_out) {
    __shared__ float red[256];
    __shared__ float linv_s;
    const int b = blockIdx.x;
    const int t = threadIdx.x;

    const float4* wt4 = (const float4*)(wtilde + (size_t)b * SS);
    float4 vals[4];
    float l = 0.f;
#pragma unroll
    for (int i = 0; i < 4; ++i) {
        vals[i] = wt4[i * 256 + t];
        l += vals[i].x + vals[i].y + vals[i].z + vals[i].w;
    }
    red[t] = l;
    __syncthreads();
    for (int off = 128; off > 0; off >>= 1) {
        if (t < off) red[t] += red[t + off];
        __syncthreads();
    }
    if (t == 0) linv_s = 1.f / red[0];
    __syncthreads();
    const float linv = linv_s;

    float4* wo4 = (float4*)(weights_out + (size_t)b * SS);
#pragma unroll
    for (int i = 0; i < 4; ++i) {
        const float4 v = vals[i];
        wo4[i * 256 + t] =
            make_float4(v.x * linv, v.y * linv, v.z * linv, v.w * linv);
    }

    float a = 0.f;
#pragma unroll 8
    for (int c = 0; c < 64; ++c)
        a += part[((size_t)(b * 64 + c)) * HH + t];
    ctx_out[b * HH + t] = a * linv;
}

// ---------------------------------------------------------------------------
extern "C" void kernel_launch(void* const* d_in, const int* in_sizes, int n_in,
                              void* d_out, int out_size, void* d_ws, size_t ws_size,
                              hipStream_t stream) {
    const float* hidden = (const float*)d_in[0];
    const float* enc    = (const float*)d_in[1];
    const float* W1_w   = (const float*)d_in[2];
    const float* W1_b   = (const float*)d_in[3];
    const float* W2_w   = (const float*)d_in[4];
    const float* W2_b   = (const float*)d_in[5];
    const float* V_w    = (const float*)d_in[6];
    const float* V_b    = (const float*)d_in[7];
    (void)V_b;  // cancels in the shifted softmax

    float* out_weights = (float*)d_out;                 // B*S
    float* out_ctx     = (float*)d_out + BB * SS;       // B*H

    float* ws      = (float*)d_ws;
    float* ws_qq   = ws;                                 // 8192
    float* ws_wt   = ws_qq + BB * HH;                    // 131072
    float* ws_part = ws_wt + BB * SS;                    // 524288
    float* ws_M    = ws_part + BB * 64 * HH;             // 1
    ushort* ws_w2  = (ushort*)(ws_M + 4);                // 65536 bf16

    static bool attr_done = false;
    if (!attr_done) {
        hipFuncSetAttribute(reinterpret_cast<const void*>(score_ctx_kernel),
                            hipFuncAttributeMaxDynamicSharedMemorySize,
                            73984);
        attr_done = true;
    }

    prep_kernel<<<dim3(256 + BB + 1), dim3(256), 0, stream>>>(
        W2_w, ws_w2, hidden, W1_w, W1_b, W2_b, V_w, ws_qq, ws_M);
    score_ctx_kernel<<<dim3(SS / 64, BB), dim3(256), 73984, stream>>>(
        enc, ws_w2, ws_qq, V_w, ws_M, ws_wt, ws_part);
    finish_kernel<<<dim3(BB), dim3(256), 0, stream>>>(
        ws_wt, ws_part, out_weights, out_ctx);
}

// Round 8
// 237.009 us; speedup vs baseline: 1.0151x; 1.0151x over previous
//
#include <hip/hip_runtime.h>
#include <hip/hip_bf16.h>
#include <math.h>

#define BB 32
#define SS 4096
#define HH 256

typedef __bf16 bf16x8 __attribute__((ext_vector_type(8)));
typedef float f32x4 __attribute__((ext_vector_type(4)));

#define GLOBAL_AS __attribute__((address_space(1)))
#define LDS_AS    __attribute__((address_space(3)))

__device__ inline bf16x8 cvt8(const float4& x, const float4& y) {
    union { __hip_bfloat162 p[4]; bf16x8 v; } u;
    u.p[0] = __float22bfloat162_rn(make_float2(x.x, x.y));
    u.p[1] = __float22bfloat162_rn(make_float2(x.z, x.w));
    u.p[2] = __float22bfloat162_rn(make_float2(y.x, y.y));
    u.p[3] = __float22bfloat162_rn(make_float2(y.z, y.w));
    return u.v;
}

// tanh(x) = 1 - 2/(e^{2x}+1). Clamp-free: exp2 overflow -> +inf -> rcp=0 -> 1;
// underflow -> 0 -> 1-2 = -1. ~5 VALU ops.
__device__ inline float fast_tanh(float x) {
    float e = __builtin_amdgcn_exp2f(x * 2.8853900817779268f);  // 2*log2(e)
    return 1.f - 2.f * __builtin_amdgcn_rcpf(e + 1.f);
}

// ---------------------------------------------------------------------------
// Prep (unchanged): blocks 0..255 swizzle W2 -> bf16 MFMA-B order;
// blocks 256..287: qq[b][h] = hidden[b]@W1[:,h] + W1_b[h] + W2_b[h];
// block 288: M = sum_h |V_w[h]|  (upper bound on V.tanh; V_b cancels).
// w2sw[((kc*16+nt)*64+lane)*8+j] = W2[kc*32+(lane>>4)*8+j][nt*16+(lane&15)]
// ---------------------------------------------------------------------------
__global__ void prep_kernel(const float* __restrict__ W2_w,
                            ushort* __restrict__ w2sw,
                            const float* __restrict__ hidden,
                            const float* __restrict__ W1_w,
                            const float* __restrict__ W1_b,
                            const float* __restrict__ W2_b,
                            const float* __restrict__ V_w,
                            float* __restrict__ qq,
                            float* __restrict__ Mout) {
    __shared__ float red[HH];
    const int t = threadIdx.x;
    if (blockIdx.x < 256) {
        const int i = blockIdx.x * 256 + t;
        const int j    = i & 7;
        const int lane = (i >> 3) & 63;
        const int nt   = (i >> 9) & 15;
        const int kc   = i >> 13;
        const int k = kc * 32 + ((lane >> 4) & 3) * 8 + j;
        const int n = nt * 16 + (lane & 15);
        __hip_bfloat16 h = __float2bfloat16(W2_w[k * HH + n]);
        w2sw[i] = *(ushort*)&h;
    } else if (blockIdx.x < 256 + BB) {
        const int b = blockIdx.x - 256;
        red[t] = hidden[b * HH + t];
        __syncthreads();
        float acc = 0.f;
#pragma unroll 16
        for (int k = 0; k < HH; ++k)
            acc = fmaf(red[k], W1_w[k * HH + t], acc);
        qq[b * HH + t] = acc + W1_b[t] + W2_b[t];
    } else {
        red[t] = fabsf(V_w[t]);
        __syncthreads();
        for (int off = 128; off > 0; off >>= 1) {
            if (t < off) red[t] += red[t + off];
            __syncthreads();
        }
        if (t == 0) Mout[0] = red[0];
    }
}

// ---------------------------------------------------------------------------
// Fused score + partial-context v8: grid (SS/64, BB), block 256 = 4 waves
// (2m x 2n), 64-row tile. ROUNDS 0-7 LESSON: every variant read enc 128 B
// per row per K-step (granule stride 1 KB; whole chip on the same
// col-window at once) -> ~1.3-2.2 TB/s effective HBM on the only stream
// that matters, invariant under pipeline depth. v8 makes the enc read
// CONTIGUOUS and SINGLE-PASS: the whole 64x256 f32 A-tile (64 KB) is
// DMA'd to LDS in sequential 1-KB-per-inst bursts at block start (bank-XOR
// applied on the SOURCE address per rule #21: linear dest, swizzled src,
// XOR'd reads). K-loop is then barrier-free and HBM-free: A-frags ds_read
// from resident LDS; W2 fragments load straight from global (lane-contig
// 16 B, 128-KB array -> L2-hot) with 1-ahead reg prefetch (two named
// sets, no unroll explosion). Ctx phase reads enc from LDS (exact f32) —
// the second enc pass is gone. LDS 68.25 KB -> 2 blocks/CU;
// __launch_bounds__(256,2) leaves 256 VGPRs (no spills).
// ---------------------------------------------------------------------------
__global__ __launch_bounds__(256, 2)
void score_ctx_kernel(const float* __restrict__ enc,
                      const ushort* __restrict__ w2sw,
                      const float* __restrict__ qq,
                      const float* __restrict__ V_w,
                      const float* __restrict__ Mptr,
                      float* __restrict__ wtilde,
                      float* __restrict__ part) {
    // [0,65536): A-tile, rows 64 x 256 f32, 16-B groups XOR-swizzled by row
    // [65536,65792): sc_lds[64]; [65792,69888): accl[4][256]
    extern __shared__ __align__(16) char smem[];
    float* sc_lds = (float*)(smem + 65536);
    float* accl   = (float*)(smem + 65792);

    const int t    = threadIdx.x;
    const int b    = blockIdx.y;
    const int c    = blockIdx.x;
    const int s0   = c * 64;
    const int wave = t >> 6;
    const int lane = t & 63;
    const int mw   = wave & 1;
    const int nw   = wave >> 1;
    const int l15  = lane & 15;
    const int quad = lane >> 4;

    const float* encA = enc + ((size_t)(b * SS + s0)) * HH;

    // ---- Stage A-tile contiguously: inst i of wave w reads row i*4+w as
    // one 1-KB burst (lanes permuted within 128-B windows = the swizzle).
    // lds[row][g'] holds enc[row][4*(g'^(row&7)) ..+3]  (g' = 16-B group)
    {
        const int g = lane;   // stored group = lane
#pragma unroll
        for (int i = 0; i < 16; ++i) {
            const int row = i * 4 + wave;
            const int srcf = row * HH + 4 * (g ^ (row & 7));
            __builtin_amdgcn_global_load_lds(
                (const GLOBAL_AS void*)(encA + srcf),
                (LDS_AS void*)(smem + i * 4096 + t * 16), 16, 0, 0);
        }
    }
    __syncthreads();   // vmcnt(0) drain + barrier: A resident (once)

    f32x4 acc[2][8];
#pragma unroll
    for (int mt = 0; mt < 2; ++mt)
#pragma unroll
        for (int nt = 0; nt < 8; ++nt) acc[mt][nt] = (f32x4)0.f;

    // W2 fragment base: lane-contiguous 16 B per (kc,nt), stride 1 KB. L2-hot.
    const ushort* w2l = w2sw + (size_t)lane * 8 + (size_t)nw * 8 * 512;

#define LOADW(DST, KC)                                                        \
    _Pragma("unroll")                                                         \
    for (int nt_ = 0; nt_ < 8; ++nt_)                                         \
        DST[nt_] = *(const bf16x8*)(w2l + ((KC) * 16 + nt_) * 512);

    const int r0 = mw * 32 + l15;
    const int rs = l15 & 7;                      // row&7 for r0 and r0+16
    const char* arow0 = smem + r0 * 1024;
    const char* arow1 = smem + (r0 + 16) * 1024;

#define COMPUTE(KC, BF)                                                       \
    do {                                                                      \
        const int gb_ = (KC) * 128;                                           \
        const float4 ax0 = *(const float4*)(arow0 + gb_ + (((quad * 2)     ^ rs) * 16)); \
        const float4 ay0 = *(const float4*)(arow0 + gb_ + (((quad * 2 + 1) ^ rs) * 16)); \
        const float4 ax1 = *(const float4*)(arow1 + gb_ + (((quad * 2)     ^ rs) * 16)); \
        const float4 ay1 = *(const float4*)(arow1 + gb_ + (((quad * 2 + 1) ^ rs) * 16)); \
        const bf16x8 af0 = cvt8(ax0, ay0);                                    \
        const bf16x8 af1 = cvt8(ax1, ay1);                                    \
        _Pragma("unroll")                                                     \
        for (int nt_ = 0; nt_ < 8; ++nt_) {                                   \
            acc[0][nt_] = __builtin_amdgcn_mfma_f32_16x16x32_bf16(            \
                af0, BF[nt_], acc[0][nt_], 0, 0, 0);                          \
            acc[1][nt_] = __builtin_amdgcn_mfma_f32_16x16x32_bf16(            \
                af1, BF[nt_], acc[1][nt_], 0, 0, 0);                          \
        }                                                                     \
    } while (0)

    // Barrier-free K-loop, 1-ahead W2 prefetch via two named register sets.
    bf16x8 bA[8], bB[8];
    LOADW(bA, 0);
#pragma unroll 1
    for (int kc = 0; kc < 8; kc += 2) {
        LOADW(bB, kc + 1);
        COMPUTE(kc, bA);
        if (kc < 6) LOADW(bA, kc + 2);
        COMPUTE(kc + 1, bB);
    }
#undef LOADW
#undef COMPUTE

    // Epilogue: C layout col = l15, local row = quad*4 + r.
    float p[2][4] = {{0.f, 0.f, 0.f, 0.f}, {0.f, 0.f, 0.f, 0.f}};
#pragma unroll
    for (int nt = 0; nt < 8; ++nt) {
        const int n = nw * 128 + nt * 16 + l15;
        const float qn = qq[b * HH + n];
        const float vn = V_w[n];
#pragma unroll
        for (int mt = 0; mt < 2; ++mt)
#pragma unroll
            for (int r = 0; r < 4; ++r)
                p[mt][r] = fmaf(vn, fast_tanh(qn + acc[mt][nt][r]), p[mt][r]);
    }
#pragma unroll
    for (int off = 1; off < 16; off <<= 1)
#pragma unroll
        for (int mt = 0; mt < 2; ++mt)
#pragma unroll
            for (int r = 0; r < 4; ++r)
                p[mt][r] += __shfl_xor(p[mt][r], off);

    if (nw == 0 && l15 == 0) {
#pragma unroll
        for (int mt = 0; mt < 2; ++mt)
            *(float4*)&sc_lds[mw * 32 + mt * 16 + quad * 4] =
                make_float4(p[mt][0], p[mt][1], p[mt][2], p[mt][3]);
    }
    __syncthreads();
    const float Mv = Mptr[0];
    if (nw == 1 && l15 == 0) {
#pragma unroll
        for (int mt = 0; mt < 2; ++mt) {
            const int row = mw * 32 + mt * 16 + quad * 4;
            float4 h = *(const float4*)&sc_lds[row];
            float4 v = make_float4(__expf(h.x + p[mt][0] - Mv),
                                   __expf(h.y + p[mt][1] - Mv),
                                   __expf(h.z + p[mt][2] - Mv),
                                   __expf(h.w + p[mt][3] - Mv));
            *(float4*)&sc_lds[row] = v;
            *(float4*)&wtilde[b * SS + s0 + row] = v;
        }
    }
    __syncthreads();

    // Ctx partial from the LDS-resident A-tile (exact f32; no 2nd enc pass).
    // Thread t owns global col-group g = t&63; stored group = g ^ (j&7).
    {
        const int tr = t >> 6;
        const int g  = t & 63;
        float4 a = make_float4(0.f, 0.f, 0.f, 0.f);
#pragma unroll
        for (int jj = 0; jj < 16; ++jj) {
            const int j = jj * 4 + tr;
            const float4 e =
                *(const float4*)(smem + j * 1024 + ((g ^ (j & 7)) * 16));
            const float w = sc_lds[j];
            a.x = fmaf(w, e.x, a.x);
            a.y = fmaf(w, e.y, a.y);
            a.z = fmaf(w, e.z, a.z);
            a.w = fmaf(w, e.w, a.w);
        }
        *(float4*)&accl[tr * HH + g * 4] = a;
    }
    __syncthreads();

    part[((size_t)(b * 64 + c)) * HH + t] =
        accl[0 * HH + t] + accl[1 * HH + t] + accl[2 * HH + t] +
        accl[3 * HH + t];
}

// ---------------------------------------------------------------------------
// Finish: grid (BB), block 256. l = sum_s wtilde; weights = wtilde/l;
// ctx = (sum_c part)/l.  (64 partials per b.)
// ---------------------------------------------------------------------------
__global__ __launch_bounds__(256)
void finish_kernel(const float* __restrict__ wtilde,
                   const float* __restrict__ part,
                   float* __restrict__ weights_out,
                   float* __restrict__ ctx_out) {
    __shared__ float red[256];
    __shared__ float linv_s;
    const int b = blockIdx.x;
    const int t = threadIdx.x;

    const float4* wt4 = (const float4*)(wtilde + (size_t)b * SS);
    float4 vals[4];
    float l = 0.f;
#pragma unroll
    for (int i = 0; i < 4; ++i) {
        vals[i] = wt4[i * 256 + t];
        l += vals[i].x + vals[i].y + vals[i].z + vals[i].w;
    }
    red[t] = l;
    __syncthreads();
    for (int off = 128; off > 0; off >>= 1) {
        if (t < off) red[t] += red[t + off];
        __syncthreads();
    }
    if (t == 0) linv_s = 1.f / red[0];
    __syncthreads();
    const float linv = linv_s;

    float4* wo4 = (float4*)(weights_out + (size_t)b * SS);
#pragma unroll
    for (int i = 0; i < 4; ++i) {
        const float4 v = vals[i];
        wo4[i * 256 + t] =
            make_float4(v.x * linv, v.y * linv, v.z * linv, v.w * linv);
    }

    float a = 0.f;
#pragma unroll 8
    for (int c = 0; c < 64; ++c)
        a += part[((size_t)(b * 64 + c)) * HH + t];
    ctx_out[b * HH + t] = a * linv;
}

// ---------------------------------------------------------------------------
extern "C" void kernel_launch(void* const* d_in, const int* in_sizes, int n_in,
                              void* d_out, int out_size, void* d_ws, size_t ws_size,
                              hipStream_t stream) {
    const float* hidden = (const float*)d_in[0];
    const float* enc    = (const float*)d_in[1];
    const float* W1_w   = (const float*)d_in[2];
    const float* W1_b   = (const float*)d_in[3];
    const float* W2_w   = (const float*)d_in[4];
    const float* W2_b   = (const float*)d_in[5];
    const float* V_w    = (const float*)d_in[6];
    const float* V_b    = (const float*)d_in[7];
    (void)V_b;  // cancels in the shifted softmax

    float* out_weights = (float*)d_out;                 // B*S
    float* out_ctx     = (float*)d_out + BB * SS;       // B*H

    float* ws      = (float*)d_ws;
    float* ws_qq   = ws;                                 // 8192
    float* ws_wt   = ws_qq + BB * HH;                    // 131072
    float* ws_part = ws_wt + BB * SS;                    // 524288
    float* ws_M    = ws_part + BB * 64 * HH;             // 1
    ushort* ws_w2  = (ushort*)(ws_M + 4);                // 65536 bf16

    static bool attr_done = false;
    if (!attr_done) {
        hipFuncSetAttribute(reinterpret_cast<const void*>(score_ctx_kernel),
                            hipFuncAttributeMaxDynamicSharedMemorySize,
                            69888);
        attr_done = true;
    }

    prep_kernel<<<dim3(256 + BB + 1), dim3(256), 0, stream>>>(
        W2_w, ws_w2, hidden, W1_w, W1_b, W2_b, V_w, ws_qq, ws_M);
    score_ctx_kernel<<<dim3(SS / 64, BB), dim3(256), 69888, stream>>>(
        enc, ws_w2, ws_qq, V_w, ws_M, ws_wt, ws_part);
    finish_kernel<<<dim3(BB), dim3(256), 0, stream>>>(
        ws_wt, ws_part, out_weights, out_ctx);
}

// Round 9
// 227.203 us; speedup vs baseline: 1.0589x; 1.0432x over previous
//
#include <hip/hip_runtime.h>
#include <hip/hip_bf16.h>
#include <math.h>

#define BB 32
#define SS 4096
#define HH 256

typedef __bf16 bf16x8 __attribute__((ext_vector_type(8)));
typedef float f32x4 __attribute__((ext_vector_type(4)));

#define GLOBAL_AS __attribute__((address_space(1)))
#define LDS_AS    __attribute__((address_space(3)))

__device__ inline bf16x8 cvt8(const float4& x, const float4& y) {
    union { __hip_bfloat162 p[4]; bf16x8 v; } u;
    u.p[0] = __float22bfloat162_rn(make_float2(x.x, x.y));
    u.p[1] = __float22bfloat162_rn(make_float2(x.z, x.w));
    u.p[2] = __float22bfloat162_rn(make_float2(y.x, y.y));
    u.p[3] = __float22bfloat162_rn(make_float2(y.z, y.w));
    return u.v;
}

// tanh(x) = 1 - 2/(e^{2x}+1). Clamp-free: exp2 overflow -> +inf -> rcp=0 -> 1;
// underflow -> 0 -> 1-2 = -1. ~5 VALU ops.
__device__ inline float fast_tanh(float x) {
    float e = __builtin_amdgcn_exp2f(x * 2.8853900817779268f);  // 2*log2(e)
    return 1.f - 2.f * __builtin_amdgcn_rcpf(e + 1.f);
}

// ---------------------------------------------------------------------------
// Prep (unchanged): blocks 0..255 swizzle W2 -> bf16 MFMA-B order;
// blocks 256..287: qq[b][h] = hidden[b]@W1[:,h] + W1_b[h] + W2_b[h];
// block 288: M = sum_h |V_w[h]|  (upper bound on V.tanh; V_b cancels).
// w2sw[((kc*16+nt)*64+lane)*8+j] = W2[kc*32+(lane>>4)*8+j][nt*16+(lane&15)]
// ---------------------------------------------------------------------------
__global__ void prep_kernel(const float* __restrict__ W2_w,
                            ushort* __restrict__ w2sw,
                            const float* __restrict__ hidden,
                            const float* __restrict__ W1_w,
                            const float* __restrict__ W1_b,
                            const float* __restrict__ W2_b,
                            const float* __restrict__ V_w,
                            float* __restrict__ qq,
                            float* __restrict__ Mout) {
    __shared__ float red[HH];
    const int t = threadIdx.x;
    if (blockIdx.x < 256) {
        const int i = blockIdx.x * 256 + t;
        const int j    = i & 7;
        const int lane = (i >> 3) & 63;
        const int nt   = (i >> 9) & 15;
        const int kc   = i >> 13;
        const int k = kc * 32 + ((lane >> 4) & 3) * 8 + j;
        const int n = nt * 16 + (lane & 15);
        __hip_bfloat16 h = __float2bfloat16(W2_w[k * HH + n]);
        w2sw[i] = *(ushort*)&h;
    } else if (blockIdx.x < 256 + BB) {
        const int b = blockIdx.x - 256;
        red[t] = hidden[b * HH + t];
        __syncthreads();
        float acc = 0.f;
#pragma unroll 16
        for (int k = 0; k < HH; ++k)
            acc = fmaf(red[k], W1_w[k * HH + t], acc);
        qq[b * HH + t] = acc + W1_b[t] + W2_b[t];
    } else {
        red[t] = fabsf(V_w[t]);
        __syncthreads();
        for (int off = 128; off > 0; off >>= 1) {
            if (t < off) red[t] += red[t + off];
            __syncthreads();
        }
        if (t == 0) Mout[0] = red[0];
    }
}

// ---------------------------------------------------------------------------
// Fused score + partial-context v9: grid (8, BB) = 256 blocks = 1/CU
// (persistent), block 512 = 8 waves (2m x 4n). ROUNDS 0-8 LESSON: all
// variants had chip-wide {stage->drain->compute} phase convoy (HBM
// saturated then idle; time = stage_total + compute_total) and R8 added
// 512 MB of W2 L2 re-streaming. v9: (1) W2 n-slice lives in 128 VGPRs per
// thread (wreg[8][4], constant-indexed full unroll -> stays in regs; L2
// traffic 512->32 MB); (2) rolling tile pipeline: per tile, issue
// STAGE(tau+1) -> vmcnt(8) (tau landed, tau+1 in flight) -> raw s_barrier
// -> compute tau. The next tile's 64-KB stage rides under the current
// tile's compute -> continuous per-CU HBM demand, no convoy. A-tile keeps
// R8's verified swizzle (linear DMA dest, source col ^ (row&7), XOR'd
// reads). Ctx from LDS (single enc pass). LDS 129.2 KB double-buffered,
// 1 block/CU; __launch_bounds__(512,2) -> 256-VGPR cap (live ~220).
// ---------------------------------------------------------------------------
__global__ __launch_bounds__(512, 2)
void score_ctx_kernel(const float* __restrict__ enc,
                      const ushort* __restrict__ w2sw,
                      const float* __restrict__ qq,
                      const float* __restrict__ V_w,
                      const float* __restrict__ Mptr,
                      float* __restrict__ wtilde,
                      float* __restrict__ part) {
    // [0,131072): abuf[2][64 rows][256 f32], 16-B groups XOR-swizzled by row
    // [131072,132096): sc[4][64]; [132096,132352): wf[64]
    // accl[8][256] aliases abuf[0] after the tile loop (last ctx reads buf 1)
    extern __shared__ __align__(16) char smem[];
    float* sc   = (float*)(smem + 131072);
    float* wf   = (float*)(smem + 132096);
    float* accl = (float*)smem;

    const int t    = threadIdx.x;
    const int b    = blockIdx.y;
    const int cx   = blockIdx.x;        // 0..7: rows cx*512 .. +512
    const int wid  = t >> 6;            // 0..7
    const int lane = t & 63;
    const int mw   = wid & 1;
    const int nw   = wid >> 1;          // 0..3: cols nw*64 .. +64
    const int l15  = lane & 15;
    const int quad = lane >> 4;
    const int g    = t & 63;            // ctx col-group

    const float* encB = enc + ((size_t)(b * SS + cx * 512)) * HH;

    // W2 n-slice -> registers, once (constant indices: stays in VGPRs).
    bf16x8 wreg[8][4];
    {
        const ushort* w2l = w2sw + lane * 8;
#pragma unroll
        for (int kc = 0; kc < 8; ++kc)
#pragma unroll
            for (int ntl = 0; ntl < 4; ++ntl)
                wreg[kc][ntl] = *(const bf16x8*)
                    (w2l + (size_t)(kc * 16 + nw * 4 + ntl) * 512);
    }
    float qv[4], vv[4];
#pragma unroll
    for (int ntl = 0; ntl < 4; ++ntl) {
        const int n = nw * 64 + ntl * 16 + l15;
        qv[ntl] = qq[b * HH + n];
        vv[ntl] = V_w[n];
    }
    const float Mv = Mptr[0];

    // Stage tile TAU -> abuf[TAU&1]: 8 waves x 8 insts x 1 KB = 64 KB.
    // Sweep i: row = i*8 + wid; source col pre-swizzled (rule #21) so
    // lds[row][g'] = enc[row][4*(g'^(row&7))..+3]  (row&7 == wid here).
#define STAGE(TAU)                                                            \
    do {                                                                      \
        const float* src_ = encB + (size_t)((TAU) * 64 + wid) * HH;           \
        char* dst_ = smem + (((TAU) & 1) * 65536) + wid * 1024 + lane * 16;   \
        _Pragma("unroll")                                                     \
        for (int i_ = 0; i_ < 8; ++i_)                                        \
            __builtin_amdgcn_global_load_lds(                                 \
                (const GLOBAL_AS void*)(src_ + (size_t)i_ * 8 * HH +          \
                                        4 * (lane ^ wid)),                    \
                (LDS_AS void*)(dst_ + i_ * 8192), 16, 0, 0);                  \
    } while (0)

    float4 cacc = make_float4(0.f, 0.f, 0.f, 0.f);

    STAGE(0);   // prologue
#pragma unroll 1
    for (int tau = 0; tau < 8; ++tau) {
        if (tau < 7) {
            STAGE(tau + 1);                               // 8 more in flight
            asm volatile("s_waitcnt vmcnt(8)" ::: "memory");  // tile tau landed
        } else {
            asm volatile("s_waitcnt vmcnt(0)" ::: "memory");
        }
        __builtin_amdgcn_s_barrier();                     // publish tile tau

        const char* ab    = smem + ((tau & 1) * 65536);
        const char* arow0 = ab + (mw * 32 + l15) * 1024;
        const char* arow1 = arow0 + 16 * 1024;
        const int rs = l15 & 7;

        f32x4 acc[2][4];
#pragma unroll
        for (int mt = 0; mt < 2; ++mt)
#pragma unroll
            for (int ntl = 0; ntl < 4; ++ntl) acc[mt][ntl] = (f32x4)0.f;

#pragma unroll
        for (int kc = 0; kc < 8; ++kc) {
            const int gb = kc * 128;
            const float4 ax0 = *(const float4*)(arow0 + gb + (((quad * 2)     ^ rs) * 16));
            const float4 ay0 = *(const float4*)(arow0 + gb + (((quad * 2 + 1) ^ rs) * 16));
            const float4 ax1 = *(const float4*)(arow1 + gb + (((quad * 2)     ^ rs) * 16));
            const float4 ay1 = *(const float4*)(arow1 + gb + (((quad * 2 + 1) ^ rs) * 16));
            const bf16x8 af0 = cvt8(ax0, ay0);
            const bf16x8 af1 = cvt8(ax1, ay1);
#pragma unroll
            for (int ntl = 0; ntl < 4; ++ntl) {
                acc[0][ntl] = __builtin_amdgcn_mfma_f32_16x16x32_bf16(
                    af0, wreg[kc][ntl], acc[0][ntl], 0, 0, 0);
                acc[1][ntl] = __builtin_amdgcn_mfma_f32_16x16x32_bf16(
                    af1, wreg[kc][ntl], acc[1][ntl], 0, 0, 0);
            }
        }

        // Scores over this wave's 64-col slice. C: col=l15, row=quad*4+r.
        float p[2][4] = {{0.f, 0.f, 0.f, 0.f}, {0.f, 0.f, 0.f, 0.f}};
#pragma unroll
        for (int ntl = 0; ntl < 4; ++ntl)
#pragma unroll
            for (int mt = 0; mt < 2; ++mt)
#pragma unroll
                for (int r = 0; r < 4; ++r)
                    p[mt][r] = fmaf(vv[ntl],
                                    fast_tanh(qv[ntl] + acc[mt][ntl][r]),
                                    p[mt][r]);
#pragma unroll
        for (int off = 1; off < 16; off <<= 1)
#pragma unroll
            for (int mt = 0; mt < 2; ++mt)
#pragma unroll
                for (int r = 0; r < 4; ++r)
                    p[mt][r] += __shfl_xor(p[mt][r], off);

        if (l15 == 0) {
#pragma unroll
            for (int mt = 0; mt < 2; ++mt)
                *(float4*)&sc[nw * 64 + mw * 32 + mt * 16 + quad * 4] =
                    make_float4(p[mt][0], p[mt][1], p[mt][2], p[mt][3]);
        }
        asm volatile("s_waitcnt lgkmcnt(0)" ::: "memory");
        __builtin_amdgcn_s_barrier();                     // sc complete

        if (t < 64) {
            const float s = sc[t] + sc[64 + t] + sc[128 + t] + sc[192 + t];
            const float w = __expf(s - Mv);
            wf[t] = w;
            wtilde[(size_t)b * SS + cx * 512 + tau * 64 + t] = w;
        }
        asm volatile("s_waitcnt lgkmcnt(0)" ::: "memory");
        __builtin_amdgcn_s_barrier();                     // wf complete

        // Ctx partial from the LDS-resident tile (exact f32, no 2nd pass).
#pragma unroll
        for (int jj = 0; jj < 8; ++jj) {
            const int j = jj * 8 + wid;
            const float4 e =
                *(const float4*)(ab + j * 1024 + ((g ^ (j & 7)) * 16));
            const float w = wf[j];
            cacc.x = fmaf(w, e.x, cacc.x);
            cacc.y = fmaf(w, e.y, cacc.y);
            cacc.z = fmaf(w, e.z, cacc.z);
            cacc.w = fmaf(w, e.w, cacc.w);
        }
        asm volatile("s_waitcnt lgkmcnt(0)" ::: "memory");
        __builtin_amdgcn_s_barrier();   // tile reads done: buf reusable
    }
#undef STAGE

    // Block reduce ctx partials (accl aliases abuf[0]; last ctx read buf 1).
    *(float4*)&accl[wid * HH + g * 4] = cacc;
    __syncthreads();
    if (t < HH) {
        float s = 0.f;
#pragma unroll
        for (int w = 0; w < 8; ++w) s += accl[w * HH + t];
        part[((size_t)(b * 8 + cx)) * HH + t] = s;
    }
}

// ---------------------------------------------------------------------------
// Finish: grid (BB), block 256. l = sum_s wtilde; weights = wtilde/l;
// ctx = (sum_c part)/l.  (8 partials per b.)
// ---------------------------------------------------------------------------
__global__ __launch_bounds__(256)
void finish_kernel(const float* __restrict__ wtilde,
                   const float* __restrict__ part,
                   float* __restrict__ weights_out,
                   float* __restrict__ ctx_out) {
    __shared__ float red[256];
    __shared__ float linv_s;
    const int b = blockIdx.x;
    const int t = threadIdx.x;

    const float4* wt4 = (const float4*)(wtilde + (size_t)b * SS);
    float4 vals[4];
    float l = 0.f;
#pragma unroll
    for (int i = 0; i < 4; ++i) {
        vals[i] = wt4[i * 256 + t];
        l += vals[i].x + vals[i].y + vals[i].z + vals[i].w;
    }
    red[t] = l;
    __syncthreads();
    for (int off = 128; off > 0; off >>= 1) {
        if (t < off) red[t] += red[t + off];
        __syncthreads();
    }
    if (t == 0) linv_s = 1.f / red[0];
    __syncthreads();
    const float linv = linv_s;

    float4* wo4 = (float4*)(weights_out + (size_t)b * SS);
#pragma unroll
    for (int i = 0; i < 4; ++i) {
        const float4 v = vals[i];
        wo4[i * 256 + t] =
            make_float4(v.x * linv, v.y * linv, v.z * linv, v.w * linv);
    }

    float a = 0.f;
#pragma unroll
    for (int c = 0; c < 8; ++c)
        a += part[((size_t)(b * 8 + c)) * HH + t];
    ctx_out[b * HH + t] = a * linv;
}

// ---------------------------------------------------------------------------
extern "C" void kernel_launch(void* const* d_in, const int* in_sizes, int n_in,
                              void* d_out, int out_size, void* d_ws, size_t ws_size,
                              hipStream_t stream) {
    const float* hidden = (const float*)d_in[0];
    const float* enc    = (const float*)d_in[1];
    const float* W1_w   = (const float*)d_in[2];
    const float* W1_b   = (const float*)d_in[3];
    const float* W2_w   = (const float*)d_in[4];
    const float* W2_b   = (const float*)d_in[5];
    const float* V_w    = (const float*)d_in[6];
    const float* V_b    = (const float*)d_in[7];
    (void)V_b;  // cancels in the shifted softmax

    float* out_weights = (float*)d_out;                 // B*S
    float* out_ctx     = (float*)d_out + BB * SS;       // B*H

    float* ws      = (float*)d_ws;
    float* ws_qq   = ws;                                 // 8192
    float* ws_wt   = ws_qq + BB * HH;                    // 131072
    float* ws_part = ws_wt + BB * SS;                    // (region reserved)
    float* ws_M    = ws_part + BB * 64 * HH;             // 1
    ushort* ws_w2  = (ushort*)(ws_M + 4);                // 65536 bf16

    static bool attr_done = false;
    if (!attr_done) {
        hipFuncSetAttribute(reinterpret_cast<const void*>(score_ctx_kernel),
                            hipFuncAttributeMaxDynamicSharedMemorySize,
                            132352);
        attr_done = true;
    }

    prep_kernel<<<dim3(256 + BB + 1), dim3(256), 0, stream>>>(
        W2_w, ws_w2, hidden, W1_w, W1_b, W2_b, V_w, ws_qq, ws_M);
    score_ctx_kernel<<<dim3(8, BB), dim3(512), 132352, stream>>>(
        enc, ws_w2, ws_qq, V_w, ws_M, ws_wt, ws_part);
    finish_kernel<<<dim3(BB), dim3(256), 0, stream>>>(
        ws_wt, ws_part, out_weights, out_ctx);
}